// Round 8
// baseline (30.736 us; speedup 1.0000x reference)
//
#include <hip/hip_runtime.h>

// CrossNet (DCN cross layers): B=16384, D=1024, L=3
//   s_b     = sum_d xl[b,d] * w[l,d]
//   xl[b,d] = x0[b,d] * s_b + bias[l,d] + xl[b,d]
//
// R7 = R6 with the NT builtins fixed: __builtin_nontemporal_* requires a
// native clang vector type, not HIP_vector_type. Use ext_vector_type(4).
// NT on both x loads and out stores (each touched once per invocation);
// w/b stay default-cached (hot, reused by every wave).

#define CN_B 16384
#define CN_D 1024
#define CN_L 3
#define ROWS_PER_WAVE 2
#define WAVES_PER_BLOCK 4
#define ROWS_PER_BLOCK (ROWS_PER_WAVE * WAVES_PER_BLOCK)

typedef float f32x4 __attribute__((ext_vector_type(4)));

__device__ __forceinline__ float4 nt_load_float4(const float4* p) {
  f32x4 v = __builtin_nontemporal_load(reinterpret_cast<const f32x4*>(p));
  return make_float4(v.x, v.y, v.z, v.w);
}
__device__ __forceinline__ void nt_store_float4(float4* p, float4 v) {
  f32x4 t = {v.x, v.y, v.z, v.w};
  __builtin_nontemporal_store(t, reinterpret_cast<f32x4*>(p));
}

__global__ __launch_bounds__(256, 4) void crossnet_kernel(
    const float* __restrict__ x,
    const float* __restrict__ w,
    const float* __restrict__ bias,
    float* __restrict__ out) {
  const int tid  = threadIdx.x;
  const int wave = tid >> 6;
  const int lane = tid & 63;
  const int row0 = (blockIdx.x * WAVES_PER_BLOCK + wave) * ROWS_PER_WAVE;

  const float4* xr0 = reinterpret_cast<const float4*>(x + (size_t)row0 * CN_D);
  const float4* xr1 = reinterpret_cast<const float4*>(x + (size_t)(row0 + 1) * CN_D);

  float4 x0a[4], xla[4], x0b[4], xlb[4];
  #pragma unroll
  for (int k = 0; k < 4; ++k) {
    x0a[k] = nt_load_float4(&xr0[k * 64 + lane]);
    x0b[k] = nt_load_float4(&xr1[k * 64 + lane]);
    xla[k] = x0a[k];
    xlb[k] = x0b[k];
  }

  #pragma unroll
  for (int l = 0; l < CN_L; ++l) {
    const float4* wrow = reinterpret_cast<const float4*>(w    + l * CN_D);
    const float4* brow = reinterpret_cast<const float4*>(bias + l * CN_D);
    float4 wl[4], bl[4];
    #pragma unroll
    for (int k = 0; k < 4; ++k) {
      wl[k] = wrow[k * 64 + lane];
      bl[k] = brow[k * 64 + lane];
    }

    // independent partial dots for the two rows
    float pa = 0.0f, pb = 0.0f;
    #pragma unroll
    for (int k = 0; k < 4; ++k) {
      pa += xla[k].x * wl[k].x; pb += xlb[k].x * wl[k].x;
      pa += xla[k].y * wl[k].y; pb += xlb[k].y * wl[k].y;
      pa += xla[k].z * wl[k].z; pb += xlb[k].z * wl[k].z;
      pa += xla[k].w * wl[k].w; pb += xlb[k].w * wl[k].w;
    }

    // two interleaved 64-lane butterflies (independent -> ILP=2)
    #pragma unroll
    for (int off = 32; off > 0; off >>= 1) {
      pa += __shfl_xor(pa, off, 64);
      pb += __shfl_xor(pb, off, 64);
    }

    #pragma unroll
    for (int k = 0; k < 4; ++k) {
      xla[k].x = x0a[k].x * pa + bl[k].x + xla[k].x;
      xla[k].y = x0a[k].y * pa + bl[k].y + xla[k].y;
      xla[k].z = x0a[k].z * pa + bl[k].z + xla[k].z;
      xla[k].w = x0a[k].w * pa + bl[k].w + xla[k].w;
      xlb[k].x = x0b[k].x * pb + bl[k].x + xlb[k].x;
      xlb[k].y = x0b[k].y * pb + bl[k].y + xlb[k].y;
      xlb[k].z = x0b[k].z * pb + bl[k].z + xlb[k].z;
      xlb[k].w = x0b[k].w * pb + bl[k].w + xlb[k].w;
    }
  }

  float4* or0 = reinterpret_cast<float4*>(out + (size_t)row0 * CN_D);
  float4* or1 = reinterpret_cast<float4*>(out + (size_t)(row0 + 1) * CN_D);
  #pragma unroll
  for (int k = 0; k < 4; ++k) {
    nt_store_float4(&or0[k * 64 + lane], xla[k]);
    nt_store_float4(&or1[k * 64 + lane], xlb[k]);
  }
}

extern "C" void kernel_launch(void* const* d_in, const int* in_sizes, int n_in,
                              void* d_out, int out_size, void* d_ws, size_t ws_size,
                              hipStream_t stream) {
  const float* x    = (const float*)d_in[0];
  const float* w    = (const float*)d_in[1];
  const float* bias = (const float*)d_in[2];
  float* out        = (float*)d_out;

  crossnet_kernel<<<CN_B / ROWS_PER_BLOCK, 256, 0, stream>>>(x, w, bias, out);
}

// Round 9
// 26.493 us; speedup vs baseline: 1.1602x; 1.1602x over previous
//
#include <hip/hip_runtime.h>

// CrossNet (DCN cross layers): B=16384, D=1024, L=3
//   s_b     = sum_d xl[b,d] * w[l,d]
//   xl[b,d] = x0[b,d] * s_b + bias[l,d] + xl[b,d]
//
// R8: best-known config = R5 (2 rows/wave, NT stores ONLY, default-cached x).
// R7's experiment showed NT *loads* regress (x's L3 residency across replays
// is load-bearing: FETCH 33->67MB); NT *stores* help (write stream is pure
// L2 pollution). Stores use ext_vector_type(4) -> one global_store_dwordx4 nt.

#define CN_B 16384
#define CN_D 1024
#define CN_L 3
#define ROWS_PER_WAVE 2
#define WAVES_PER_BLOCK 4
#define ROWS_PER_BLOCK (ROWS_PER_WAVE * WAVES_PER_BLOCK)

typedef float f32x4 __attribute__((ext_vector_type(4)));

__device__ __forceinline__ void nt_store_float4(float4* p, float4 v) {
  f32x4 t = {v.x, v.y, v.z, v.w};
  __builtin_nontemporal_store(t, reinterpret_cast<f32x4*>(p));
}

__global__ __launch_bounds__(256, 4) void crossnet_kernel(
    const float* __restrict__ x,
    const float* __restrict__ w,
    const float* __restrict__ bias,
    float* __restrict__ out) {
  const int tid  = threadIdx.x;
  const int wave = tid >> 6;
  const int lane = tid & 63;
  const int row0 = (blockIdx.x * WAVES_PER_BLOCK + wave) * ROWS_PER_WAVE;

  const float4* xr0 = reinterpret_cast<const float4*>(x + (size_t)row0 * CN_D);
  const float4* xr1 = reinterpret_cast<const float4*>(x + (size_t)(row0 + 1) * CN_D);

  float4 x0a[4], xla[4], x0b[4], xlb[4];
  #pragma unroll
  for (int k = 0; k < 4; ++k) {
    x0a[k] = xr0[k * 64 + lane];
    x0b[k] = xr1[k * 64 + lane];
    xla[k] = x0a[k];
    xlb[k] = x0b[k];
  }

  #pragma unroll
  for (int l = 0; l < CN_L; ++l) {
    const float4* wrow = reinterpret_cast<const float4*>(w    + l * CN_D);
    const float4* brow = reinterpret_cast<const float4*>(bias + l * CN_D);
    float4 wl[4], bl[4];
    #pragma unroll
    for (int k = 0; k < 4; ++k) {
      wl[k] = wrow[k * 64 + lane];
      bl[k] = brow[k * 64 + lane];
    }

    // independent partial dots for the two rows
    float pa = 0.0f, pb = 0.0f;
    #pragma unroll
    for (int k = 0; k < 4; ++k) {
      pa += xla[k].x * wl[k].x; pb += xlb[k].x * wl[k].x;
      pa += xla[k].y * wl[k].y; pb += xlb[k].y * wl[k].y;
      pa += xla[k].z * wl[k].z; pb += xlb[k].z * wl[k].z;
      pa += xla[k].w * wl[k].w; pb += xlb[k].w * wl[k].w;
    }

    // two interleaved 64-lane butterflies (independent -> ILP=2)
    #pragma unroll
    for (int off = 32; off > 0; off >>= 1) {
      pa += __shfl_xor(pa, off, 64);
      pb += __shfl_xor(pb, off, 64);
    }

    #pragma unroll
    for (int k = 0; k < 4; ++k) {
      xla[k].x = x0a[k].x * pa + bl[k].x + xla[k].x;
      xla[k].y = x0a[k].y * pa + bl[k].y + xla[k].y;
      xla[k].z = x0a[k].z * pa + bl[k].z + xla[k].z;
      xla[k].w = x0a[k].w * pa + bl[k].w + xla[k].w;
      xlb[k].x = x0b[k].x * pb + bl[k].x + xlb[k].x;
      xlb[k].y = x0b[k].y * pb + bl[k].y + xlb[k].y;
      xlb[k].z = x0b[k].z * pb + bl[k].z + xlb[k].z;
      xlb[k].w = x0b[k].w * pb + bl[k].w + xlb[k].w;
    }
  }

  float4* or0 = reinterpret_cast<float4*>(out + (size_t)row0 * CN_D);
  float4* or1 = reinterpret_cast<float4*>(out + (size_t)(row0 + 1) * CN_D);
  #pragma unroll
  for (int k = 0; k < 4; ++k) {
    nt_store_float4(&or0[k * 64 + lane], xla[k]);
    nt_store_float4(&or1[k * 64 + lane], xlb[k]);
  }
}

extern "C" void kernel_launch(void* const* d_in, const int* in_sizes, int n_in,
                              void* d_out, int out_size, void* d_ws, size_t ws_size,
                              hipStream_t stream) {
  const float* x    = (const float*)d_in[0];
  const float* w    = (const float*)d_in[1];
  const float* bias = (const float*)d_in[2];
  float* out        = (float*)d_out;

  crossnet_kernel<<<CN_B / ROWS_PER_BLOCK, 256, 0, stream>>>(x, w, bias, out);
}

// Round 10
// 24.777 us; speedup vs baseline: 1.2405x; 1.0693x over previous
//
#include <hip/hip_runtime.h>

// CrossNet (DCN cross layers): B=16384, D=1024, L=3
//   s_b     = sum_d xl[b,d] * w[l,d]
//   xl[b,d] = x0[b,d] * s_b + bias[l,d] + xl[b,d]
//
// R9: exact replication of R5 (best measured, 24.6us) for an A/B against
// R8's 26.5us. Only diff vs R8: NT stores issued as 4 SCALAR component
// stores (R5 form) instead of one vector NT store. Discriminates
// scalar-NT-schedule benefit vs run-to-run noise.

#define CN_B 16384
#define CN_D 1024
#define CN_L 3
#define ROWS_PER_WAVE 2
#define WAVES_PER_BLOCK 4
#define ROWS_PER_BLOCK (ROWS_PER_WAVE * WAVES_PER_BLOCK)

__device__ __forceinline__ void nt_store_float4(float4* p, float4 v) {
  __builtin_nontemporal_store(v.x, &p->x);
  __builtin_nontemporal_store(v.y, &p->y);
  __builtin_nontemporal_store(v.z, &p->z);
  __builtin_nontemporal_store(v.w, &p->w);
}

__global__ __launch_bounds__(256, 4) void crossnet_kernel(
    const float* __restrict__ x,
    const float* __restrict__ w,
    const float* __restrict__ bias,
    float* __restrict__ out) {
  const int tid  = threadIdx.x;
  const int wave = tid >> 6;
  const int lane = tid & 63;
  const int row0 = (blockIdx.x * WAVES_PER_BLOCK + wave) * ROWS_PER_WAVE;

  const float4* xr0 = reinterpret_cast<const float4*>(x + (size_t)row0 * CN_D);
  const float4* xr1 = reinterpret_cast<const float4*>(x + (size_t)(row0 + 1) * CN_D);

  float4 x0a[4], xla[4], x0b[4], xlb[4];
  #pragma unroll
  for (int k = 0; k < 4; ++k) {
    x0a[k] = xr0[k * 64 + lane];
    x0b[k] = xr1[k * 64 + lane];
    xla[k] = x0a[k];
    xlb[k] = x0b[k];
  }

  #pragma unroll
  for (int l = 0; l < CN_L; ++l) {
    const float4* wrow = reinterpret_cast<const float4*>(w    + l * CN_D);
    const float4* brow = reinterpret_cast<const float4*>(bias + l * CN_D);
    float4 wl[4], bl[4];
    #pragma unroll
    for (int k = 0; k < 4; ++k) {
      wl[k] = wrow[k * 64 + lane];
      bl[k] = brow[k * 64 + lane];
    }

    // independent partial dots for the two rows
    float pa = 0.0f, pb = 0.0f;
    #pragma unroll
    for (int k = 0; k < 4; ++k) {
      pa += xla[k].x * wl[k].x; pb += xlb[k].x * wl[k].x;
      pa += xla[k].y * wl[k].y; pb += xlb[k].y * wl[k].y;
      pa += xla[k].z * wl[k].z; pb += xlb[k].z * wl[k].z;
      pa += xla[k].w * wl[k].w; pb += xlb[k].w * wl[k].w;
    }

    // two interleaved 64-lane butterflies (independent -> ILP=2)
    #pragma unroll
    for (int off = 32; off > 0; off >>= 1) {
      pa += __shfl_xor(pa, off, 64);
      pb += __shfl_xor(pb, off, 64);
    }

    #pragma unroll
    for (int k = 0; k < 4; ++k) {
      xla[k].x = x0a[k].x * pa + bl[k].x + xla[k].x;
      xla[k].y = x0a[k].y * pa + bl[k].y + xla[k].y;
      xla[k].z = x0a[k].z * pa + bl[k].z + xla[k].z;
      xla[k].w = x0a[k].w * pa + bl[k].w + xla[k].w;
      xlb[k].x = x0b[k].x * pb + bl[k].x + xlb[k].x;
      xlb[k].y = x0b[k].y * pb + bl[k].y + xlb[k].y;
      xlb[k].z = x0b[k].z * pb + bl[k].z + xlb[k].z;
      xlb[k].w = x0b[k].w * pb + bl[k].w + xlb[k].w;
    }
  }

  float4* or0 = reinterpret_cast<float4*>(out + (size_t)row0 * CN_D);
  float4* or1 = reinterpret_cast<float4*>(out + (size_t)(row0 + 1) * CN_D);
  #pragma unroll
  for (int k = 0; k < 4; ++k) {
    nt_store_float4(&or0[k * 64 + lane], xla[k]);
    nt_store_float4(&or1[k * 64 + lane], xlb[k]);
  }
}

extern "C" void kernel_launch(void* const* d_in, const int* in_sizes, int n_in,
                              void* d_out, int out_size, void* d_ws, size_t ws_size,
                              hipStream_t stream) {
  const float* x    = (const float*)d_in[0];
  const float* w    = (const float*)d_in[1];
  const float* bias = (const float*)d_in[2];
  float* out        = (float*)d_out;

  crossnet_kernel<<<CN_B / ROWS_PER_BLOCK, 256, 0, stream>>>(x, w, bias, out);
}